// Round 1
// baseline (371.046 us; speedup 1.0000x reference)
//
#include <hip/hip_runtime.h>

#define T_STEPS 4096
#define BATCH   2048
#define HID     10
#define UB      16   // steps per buffer; outer loop advances 2*UB (ping-pong)

// ---- R7/R8-proven load skeleton ------------------------------------------
__device__ __forceinline__ void issue16(float (&xr)[UB], const float* base) {
#pragma unroll
    for (int u = 0; u < UB; ++u)
        asm volatile("global_load_dword %0, %1, off"
                     : "=v"(xr[u]) : "v"(base + (size_t)u * BATCH) : "memory");
}
#define BIND16(a) "+v"(a[0]),"+v"(a[1]),"+v"(a[2]),"+v"(a[3]),"+v"(a[4]), \
    "+v"(a[5]),"+v"(a[6]),"+v"(a[7]),"+v"(a[8]),"+v"(a[9]),"+v"(a[10]),   \
    "+v"(a[11]),"+v"(a[12]),"+v"(a[13]),"+v"(a[14]),"+v"(a[15])
__device__ __forceinline__ void wait1_bind(float (&xr)[UB]) {
    asm volatile("s_waitcnt vmcnt(1)" : BIND16(xr) :: "memory");
}
__device__ __forceinline__ void wait0_bind(float (&xr)[UB]) {
    asm volatile("s_waitcnt vmcnt(0)" : BIND16(xr) :: "memory");
}

// ---- hand-scheduled RNN step, r-form, 4-chain accumulate (R9) -------------
// State r = 1/(exp2(C*a)+1)  (h = 1-2r folded into weights):
//   a'_t = bj2 + wih2*x_t + sum_N w2[N]*ror_N(r)   [w2=-2C*w, bj2=C*(bj+sum w)]
//   r_{t+1} = rcp(exp2(a'_t) + 1)
// R9 change: the 16-rotation matvec previously ran through TWO accumulator
// chains (c0 depth 9, c1 depth 8) -> r-dependent critical path ~9*L_dpp +
// trans tail, which left the wave issuing 1 instr per ~5.8 cyc (VALUBusy 36%).
// Now FOUR chains a0..a3 (r-dependent depth 4 each; a0's x-FMA seed is
// r-independent and pre-issues), tree-combined with 3 adds. Output p-chain
// folds and the keep-FMA are placed to fill the exp/rcp latency gaps, so only
// one pure s_nop remains. Hazard spacings preserved from the R8-proven blob:
// dependent-DPP >=3 slots, trans->consumer >=2 slots, rcp->next-read 3 slots.
// Entry: r = r_t. Exit: r = r_{t+1}. Keep of p (out row t-1) uses mask m.
__device__ __forceinline__ void step_blob(float& r, float& p, float& pk,
                                          float x, float wih2, float bj2,
                                          float wo2, float m,
                                          const float (&w)[16]) {
    float a0, a1, a2, a3;
    asm volatile(
        "v_fma_f32 %[a0], %[wih2], %[x], %[bj2]\n\t"                                   // 1  r-indep seed
        "v_mul_f32 %[p], %[wo2], %[r]\n\t"                                             // 2  out seed (r sp3 from prev rcp)
        "v_mul_f32_dpp %[a1], %[r], %[w4] row_ror:4 row_mask:0xf bank_mask:0xf\n\t"    // 3
        "v_mul_f32_dpp %[a2], %[r], %[w8] row_ror:8 row_mask:0xf bank_mask:0xf\n\t"    // 4
        "v_mul_f32_dpp %[a3], %[r], %[w12] row_ror:12 row_mask:0xf bank_mask:0xf\n\t"  // 5
        "v_fmac_f32 %[a0], %[r], %[w0]\n\t"                                            // 6
        "v_fmac_f32_dpp %[a1], %[r], %[w5] row_ror:5 row_mask:0xf bank_mask:0xf\n\t"   // 7
        "v_fmac_f32_dpp %[a2], %[r], %[w9] row_ror:9 row_mask:0xf bank_mask:0xf\n\t"   // 8
        "v_fmac_f32_dpp %[a3], %[r], %[w13] row_ror:13 row_mask:0xf bank_mask:0xf\n\t" // 9
        "v_fmac_f32_dpp %[a0], %[r], %[w1] row_ror:1 row_mask:0xf bank_mask:0xf\n\t"   // 10
        "v_fmac_f32_dpp %[a1], %[r], %[w6] row_ror:6 row_mask:0xf bank_mask:0xf\n\t"   // 11
        "v_add_f32_dpp %[p], %[p], %[p] row_ror:8 row_mask:0xf bank_mask:0xf\n\t"      // 12 (p sp10)
        "v_fmac_f32_dpp %[a2], %[r], %[w10] row_ror:10 row_mask:0xf bank_mask:0xf\n\t" // 13
        "v_fmac_f32_dpp %[a3], %[r], %[w14] row_ror:14 row_mask:0xf bank_mask:0xf\n\t" // 14
        "v_fmac_f32_dpp %[a0], %[r], %[w2] row_ror:2 row_mask:0xf bank_mask:0xf\n\t"   // 15
        "v_add_f32_dpp %[p], %[p], %[p] row_ror:4 row_mask:0xf bank_mask:0xf\n\t"      // 16 (p sp4)
        "v_fmac_f32_dpp %[a1], %[r], %[w7] row_ror:7 row_mask:0xf bank_mask:0xf\n\t"   // 17
        "v_fmac_f32_dpp %[a2], %[r], %[w11] row_ror:11 row_mask:0xf bank_mask:0xf\n\t" // 18
        "v_fmac_f32_dpp %[a3], %[r], %[w15] row_ror:15 row_mask:0xf bank_mask:0xf\n\t" // 19
        "v_add_f32_dpp %[p], %[p], %[p] row_ror:2 row_mask:0xf bank_mask:0xf\n\t"      // 20 (p sp4)
        "v_fmac_f32_dpp %[a0], %[r], %[w3] row_ror:3 row_mask:0xf bank_mask:0xf\n\t"   // 21
        "v_add_f32 %[a2], %[a2], %[a3]\n\t"                                            // 22 combine hi
        "v_add_f32 %[a0], %[a0], %[a1]\n\t"                                            // 23 combine lo
        "v_add_f32_dpp %[p], %[p], %[p] row_ror:1 row_mask:0xf bank_mask:0xf\n\t"      // 24 (p sp4)
        "v_add_f32 %[a0], %[a0], %[a2]\n\t"                                            // 25 final sum
        "v_exp_f32 %[a0], %[a0]\n\t"                                                   // 26
        "v_fmac_f32 %[pk], %[p], %[m]\n\t"                                             // 27 keep (fills trans gap; p sp3)
        "v_add_f32 %[a0], 1.0, %[a0]\n\t"                                              // 28 (exp sp2, R8-proven)
        "v_rcp_f32 %[r], %[a0]\n\t"                                                    // 29 r_{t+1}
        "s_nop 0"                                                                      // 30 trans-use wait state
        : [a0]"=&v"(a0), [a1]"=&v"(a1), [a2]"=&v"(a2), [a3]"=&v"(a3),
          [r]"+v"(r), [p]"+v"(p), [pk]"+v"(pk)
        : [x]"v"(x), [wih2]"v"(wih2), [bj2]"v"(bj2), [wo2]"v"(wo2), [m]"v"(m),
          [w0]"v"(w[0]),  [w1]"v"(w[1]),  [w2]"v"(w[2]),  [w3]"v"(w[3]),
          [w4]"v"(w[4]),  [w5]"v"(w[5]),  [w6]"v"(w[6]),  [w7]"v"(w[7]),
          [w8]"v"(w[8]),  [w9]"v"(w[9]),  [w10]"v"(w[10]),[w11]"v"(w[11]),
          [w12]"v"(w[12]),[w13]"v"(w[13]),[w14]"v"(w[14]),[w15]"v"(w[15]));
}

// Block-end finisher: seed from final r (row t0+15) and reduce. s_nop 1
// covers DPP read-after-write hazards (R8-proven).
__device__ __forceinline__ void finish_reduce(float r, float& p, float& pk,
                                              float wo2, float m15) {
    asm volatile(
        "v_mul_f32 %[p], %[wo2], %[r]\n\t"
        "s_nop 1\n\t"
        "v_add_f32_dpp %[p], %[p], %[p] row_ror:8 row_mask:0xf bank_mask:0xf\n\t"
        "s_nop 1\n\t"
        "v_add_f32_dpp %[p], %[p], %[p] row_ror:4 row_mask:0xf bank_mask:0xf\n\t"
        "s_nop 1\n\t"
        "v_add_f32_dpp %[p], %[p], %[p] row_ror:2 row_mask:0xf bank_mask:0xf\n\t"
        "s_nop 1\n\t"
        "v_add_f32_dpp %[p], %[p], %[p] row_ror:1 row_mask:0xf bank_mask:0xf\n\t"
        "s_nop 1\n\t"
        "v_fmac_f32 %[pk], %[p], %[m]"
        : [p]"+v"(p), [pk]"+v"(pk)
        : [r]"v"(r), [wo2]"v"(wo2), [m]"v"(m15));
}

__global__ __launch_bounds__(64, 1) void rnn_kernel(
    const float* __restrict__ x,
    const float* __restrict__ h0,
    const float* __restrict__ W_ih,
    const float* __restrict__ b_ih,
    const float* __restrict__ W_hh,
    const float* __restrict__ b_hh,
    const float* __restrict__ W_out,
    const float* __restrict__ b_out,
    float* __restrict__ out)
{
    const int tid = threadIdx.x;            // 0..63
    const int j   = tid & 15;               // lane-in-group; j<10 owns dim j
    const int b   = (blockIdx.x << 2) + (tid >> 4);
    const bool jv = (j < HID);
    const int jc  = jv ? j : 0;

    const float CC = 2.88539008177792681472f;   // 2*log2(e)

    // Raw per-lane weights (idle lanes zero).
    const float wih = jv ? W_ih[jc] : 0.0f;
    const float bj  = jv ? (b_ih[jc] + b_hh[jc]) : 0.0f;
    const float wo  = jv ? W_out[jc] : 0.0f;

    float wsh[16];
    float wsum = 0.0f;
#pragma unroll
    for (int N = 0; N < 16; ++N) {
        const int k = (j - N) & 15;
        wsh[N] = (jv && k < HID) ? W_hh[jc * HID + k] : 0.0f;
        wsum += wsh[N];
    }

    // r-form folded constants: a' = C*a with h = 1-2r absorbed.
    const float wih2 = CC * wih;
    const float bj2  = CC * (bj + wsum);
    float w2[16];
#pragma unroll
    for (int N = 0; N < 16; ++N) w2[N] = -2.0f * CC * wsh[N];
    const float wo2 = -2.0f * wo;
    float c0sum = b_out[0];
#pragma unroll
    for (int k = 0; k < HID; ++k) c0sum += W_out[k];   // C0 = sum(wo) + bo

    // Keep-masks.
    float km[16];
#pragma unroll
    for (int i = 0; i < 16; ++i) km[i] = (j == i) ? 1.0f : 0.0f;
    const float mzero = 0.0f;

    // r_0 = (1 - h_0)/2 ; idle lanes h0=0 -> r=0.5 (their fixed point).
    float rval = fmaf(-0.5f, jv ? h0[b * HID + jc] : 0.0f, 0.5f);
    float p = 0.0f, pk = 0.0f;

    const float* xb = x + b;
    float xA[UB], xB[UB];

    issue16(xA, xb);
    wait0_bind(xA);

    for (int t0 = 0; t0 < T_STEPS; t0 += 2 * UB) {
        // ---- half 1: consume xA, prefetch xB ----
        wait1_bind(xA);
        issue16(xB, xb + (size_t)(t0 + UB) * BATCH);
#pragma unroll
        for (int u = 0; u < UB; ++u)
            step_blob(rval, p, pk, xA[u], wih2, bj2, wo2,
                      (u == 0) ? mzero : km[u - 1], w2);
        finish_reduce(rval, p, pk, wo2, km[15]);
        out[(size_t)(t0 + j) * BATCH + b] = pk + c0sum;
        pk = 0.0f;

        // ---- half 2: consume xB, prefetch xA ----
        wait1_bind(xB);
        const float* xsrc = (t0 + 2 * UB < T_STEPS)
                          ? (xb + (size_t)(t0 + 2 * UB) * BATCH) : xb;
        issue16(xA, xsrc);
#pragma unroll
        for (int u = 0; u < UB; ++u)
            step_blob(rval, p, pk, xB[u], wih2, bj2, wo2,
                      (u == 0) ? mzero : km[u - 1], w2);
        finish_reduce(rval, p, pk, wo2, km[15]);
        out[(size_t)(t0 + UB + j) * BATCH + b] = pk + c0sum;
        pk = 0.0f;
    }

    // Drain the final speculative xA reload while registers are still bound
    // (async-clobber hazard, R6 post-mortem).
    wait0_bind(xA);

    // h_last: h = 1 - 2r
    if (jv) out[(size_t)T_STEPS * BATCH + (size_t)b * HID + j]
                = fmaf(-2.0f, rval, 1.0f);
}

extern "C" void kernel_launch(void* const* d_in, const int* in_sizes, int n_in,
                              void* d_out, int out_size, void* d_ws, size_t ws_size,
                              hipStream_t stream) {
    const float* x     = (const float*)d_in[0];
    const float* h0    = (const float*)d_in[1];
    const float* W_ih  = (const float*)d_in[2];
    const float* b_ih  = (const float*)d_in[3];
    const float* W_hh  = (const float*)d_in[4];
    const float* b_hh  = (const float*)d_in[5];
    const float* W_out = (const float*)d_in[6];
    const float* b_out = (const float*)d_in[7];

    rnn_kernel<<<BATCH / 4, 64, 0, stream>>>(
        x, h0, W_ih, b_ih, W_hh, b_hh, W_out, b_out, (float*)d_out);
}

// Round 2
// 331.096 us; speedup vs baseline: 1.1207x; 1.1207x over previous
//
#include <hip/hip_runtime.h>

#define T_STEPS 4096
#define BATCH   2048
#define HID     10
#define UB      16   // steps per buffer; outer loop advances 2*UB (ping-pong)

// ---- R7/R8-proven load skeleton ------------------------------------------
__device__ __forceinline__ void issue16(float (&xr)[UB], const float* base) {
#pragma unroll
    for (int u = 0; u < UB; ++u)
        asm volatile("global_load_dword %0, %1, off"
                     : "=v"(xr[u]) : "v"(base + (size_t)u * BATCH) : "memory");
}
#define BIND16(a) "+v"(a[0]),"+v"(a[1]),"+v"(a[2]),"+v"(a[3]),"+v"(a[4]), \
    "+v"(a[5]),"+v"(a[6]),"+v"(a[7]),"+v"(a[8]),"+v"(a[9]),"+v"(a[10]),   \
    "+v"(a[11]),"+v"(a[12]),"+v"(a[13]),"+v"(a[14]),"+v"(a[15])
__device__ __forceinline__ void wait1_bind(float (&xr)[UB]) {
    asm volatile("s_waitcnt vmcnt(1)" : BIND16(xr) :: "memory");
}
__device__ __forceinline__ void wait0_bind(float (&xr)[UB]) {
    asm volatile("s_waitcnt vmcnt(0)" : BIND16(xr) :: "memory");
}

// ---- R10: output-in-lane-10 step ------------------------------------------
// R9 post-mortem: cyc/step tracks weighted instruction count (DPP~6, VOP~4,
// trans~16 cyc for a lone wave), NOT dependency depth. So R10 deletes the
// 6-op output p-chain: lane 10 (idle in the matvec) carries W_out as its
// rotation weights (unscaled, -2*wo form), so after the accumulate its c0 =
// y - C0 for free. One fmac_dpp per step (rotation (u+5)&15 moves lane 10's
// c0 to lane u-1; mask km[u-1] keeps it) replaces seed+4 folds+keep.
// Matvec uses THREE chains c0/c1/c2 so every dependent-DPP accumulate has a
// >=3-slot gap (R8 rule; R9's gap-2 tail violated it). Tail spacing is
// byte-for-byte R8's proven pattern: exp reads sum at gap 1, s_nop 0, +1.0,
// (pk-fmac fills the slot, c0 gap 4), rcp at gap 2, s_nop 0; next blob's
// first r-read is plain at gap 3, first DPP r-read at gap 4.
// Entry: r = r_t. Exit: r = r_{t+1}.
#define STEP_HEAD \
    "v_fma_f32 %[c0], %[wih2], %[x], %[bj2]\n\t"                                   /* 1 */ \
    "v_fmac_f32 %[c0], %[r], %[w0]\n\t"                                            /* 2 plain r-read, gap3 from rcp */ \
    "v_mul_f32_dpp %[c1], %[r], %[w1] row_ror:1 row_mask:0xf bank_mask:0xf\n\t"    /* 3 */ \
    "v_mul_f32_dpp %[c2], %[r], %[w2] row_ror:2 row_mask:0xf bank_mask:0xf\n\t"    /* 4 */ \
    "v_fmac_f32_dpp %[c0], %[r], %[w3] row_ror:3 row_mask:0xf bank_mask:0xf\n\t"   /* 5  c0 gap3 */ \
    "v_fmac_f32_dpp %[c1], %[r], %[w4] row_ror:4 row_mask:0xf bank_mask:0xf\n\t"   /* 6  c1 gap3 */ \
    "v_fmac_f32_dpp %[c2], %[r], %[w5] row_ror:5 row_mask:0xf bank_mask:0xf\n\t"   /* 7  c2 gap3 */ \
    "v_fmac_f32_dpp %[c0], %[r], %[w6] row_ror:6 row_mask:0xf bank_mask:0xf\n\t"   /* 8 */ \
    "v_fmac_f32_dpp %[c1], %[r], %[w7] row_ror:7 row_mask:0xf bank_mask:0xf\n\t"   /* 9 */ \
    "v_fmac_f32_dpp %[c2], %[r], %[w8] row_ror:8 row_mask:0xf bank_mask:0xf\n\t"   /* 10 */ \
    "v_fmac_f32_dpp %[c0], %[r], %[w9] row_ror:9 row_mask:0xf bank_mask:0xf\n\t"   /* 11 */ \
    "v_fmac_f32_dpp %[c1], %[r], %[w10] row_ror:10 row_mask:0xf bank_mask:0xf\n\t" /* 12 */ \
    "v_fmac_f32_dpp %[c2], %[r], %[w11] row_ror:11 row_mask:0xf bank_mask:0xf\n\t" /* 13 */ \
    "v_fmac_f32_dpp %[c0], %[r], %[w12] row_ror:12 row_mask:0xf bank_mask:0xf\n\t" /* 14 */ \
    "v_fmac_f32_dpp %[c1], %[r], %[w13] row_ror:13 row_mask:0xf bank_mask:0xf\n\t" /* 15 */ \
    "v_fmac_f32_dpp %[c2], %[r], %[w14] row_ror:14 row_mask:0xf bank_mask:0xf\n\t" /* 16 */ \
    "v_fmac_f32_dpp %[c0], %[r], %[w15] row_ror:15 row_mask:0xf bank_mask:0xf\n\t" /* 17 */ \
    "v_add_f32 %[c1], %[c1], %[c2]\n\t"                                            /* 18 */ \
    "v_add_f32 %[c0], %[c0], %[c1]\n\t"                                            /* 19 */ \
    "v_exp_f32 %[ex], %[c0]\n\t"                                                   /* 20 gap1 (R8-proven) */ \
    "s_nop 0\n\t"                                                                  /* 21 trans-use wait */ \
    "v_add_f32 %[ex], 1.0, %[ex]\n\t"                                              /* 22 */

#define STEP_TAIL \
    "v_rcp_f32 %[r], %[ex]\n\t"                                                    /* 24 ex gap2 */ \
    "s_nop 0"                                                                      /* 25 trans-use wait */

// pk extraction line (slot 23): lane u-1 <- lane 10's c0 (gap 4 from slot 19)
#define PKDPP(N) "v_fmac_f32_dpp %[pk], %[c0], %[m] row_ror:" #N " row_mask:0xf bank_mask:0xf\n\t"
#define PKPLAIN  "v_fmac_f32 %[pk], %[c0], %[m]\n\t"

#define DEF_STEP(SUF, PKLINE_) \
__device__ __forceinline__ void step_##SUF(float& r, float& pk, float x, \
        float wih2, float bj2, float m, const float (&w)[16]) { \
    float c0, c1, c2, ex; \
    asm volatile( STEP_HEAD PKLINE_ STEP_TAIL \
        : [c0]"=&v"(c0), [c1]"=&v"(c1), [c2]"=&v"(c2), [ex]"=&v"(ex), \
          [r]"+v"(r), [pk]"+v"(pk) \
        : [x]"v"(x), [wih2]"v"(wih2), [bj2]"v"(bj2), [m]"v"(m), \
          [w0]"v"(w[0]),  [w1]"v"(w[1]),  [w2]"v"(w[2]),  [w3]"v"(w[3]), \
          [w4]"v"(w[4]),  [w5]"v"(w[5]),  [w6]"v"(w[6]),  [w7]"v"(w[7]), \
          [w8]"v"(w[8]),  [w9]"v"(w[9]),  [w10]"v"(w[10]),[w11]"v"(w[11]), \
          [w12]"v"(w[12]),[w13]"v"(w[13]),[w14]"v"(w[14]),[w15]"v"(w[15])); \
}

DEF_STEP(r0,  PKPLAIN)
DEF_STEP(r1,  PKDPP(1))
DEF_STEP(r2,  PKDPP(2))
DEF_STEP(r3,  PKDPP(3))
DEF_STEP(r4,  PKDPP(4))
DEF_STEP(r6,  PKDPP(6))
DEF_STEP(r7,  PKDPP(7))
DEF_STEP(r8,  PKDPP(8))
DEF_STEP(r9,  PKDPP(9))
DEF_STEP(r10, PKDPP(10))
DEF_STEP(r11, PKDPP(11))
DEF_STEP(r12, PKDPP(12))
DEF_STEP(r13, PKDPP(13))
DEF_STEP(r14, PKDPP(14))
DEF_STEP(r15, PKDPP(15))

// Dispatcher: blob u extracts row t0+u-1 -> lane u-1 needs ror (u-1-10)&15.
template<int U>
__device__ __forceinline__ void step_u(float& r, float& pk, float x,
                                       float wih2, float bj2,
                                       const float (&km)[16], float mz,
                                       const float (&w)[16]) {
    constexpr int ROT = (U + 5) & 15;
    float m;
    if constexpr (U == 0) m = mz; else m = km[U - 1];
    if constexpr (ROT == 0)       step_r0 (r, pk, x, wih2, bj2, m, w);
    else if constexpr (ROT == 1)  step_r1 (r, pk, x, wih2, bj2, m, w);
    else if constexpr (ROT == 2)  step_r2 (r, pk, x, wih2, bj2, m, w);
    else if constexpr (ROT == 3)  step_r3 (r, pk, x, wih2, bj2, m, w);
    else if constexpr (ROT == 4)  step_r4 (r, pk, x, wih2, bj2, m, w);
    else if constexpr (ROT == 6)  step_r6 (r, pk, x, wih2, bj2, m, w);
    else if constexpr (ROT == 7)  step_r7 (r, pk, x, wih2, bj2, m, w);
    else if constexpr (ROT == 8)  step_r8 (r, pk, x, wih2, bj2, m, w);
    else if constexpr (ROT == 9)  step_r9 (r, pk, x, wih2, bj2, m, w);
    else if constexpr (ROT == 10) step_r10(r, pk, x, wih2, bj2, m, w);
    else if constexpr (ROT == 11) step_r11(r, pk, x, wih2, bj2, m, w);
    else if constexpr (ROT == 12) step_r12(r, pk, x, wih2, bj2, m, w);
    else if constexpr (ROT == 13) step_r13(r, pk, x, wih2, bj2, m, w);
    else if constexpr (ROT == 14) step_r14(r, pk, x, wih2, bj2, m, w);
    else                          step_r15(r, pk, x, wih2, bj2, m, w);
}

template<int U>
__device__ __forceinline__ void run16(float& r, float& pk, const float (&xr)[UB],
                                      float wih2, float bj2,
                                      const float (&km)[16], float mz,
                                      const float (&w)[16]) {
    if constexpr (U < UB) {
        step_u<U>(r, pk, xr[U], wih2, bj2, km, mz, w);
        run16<U + 1>(r, pk, xr, wih2, bj2, km, mz, w);
    }
}

// Block-end finisher: seed from final r (row t0+15) and reduce. s_nop 1
// covers DPP read-after-write hazards (R8-proven).
__device__ __forceinline__ void finish_reduce(float r, float& p, float& pk,
                                              float wo2, float m15) {
    asm volatile(
        "v_mul_f32 %[p], %[wo2], %[r]\n\t"
        "s_nop 1\n\t"
        "v_add_f32_dpp %[p], %[p], %[p] row_ror:8 row_mask:0xf bank_mask:0xf\n\t"
        "s_nop 1\n\t"
        "v_add_f32_dpp %[p], %[p], %[p] row_ror:4 row_mask:0xf bank_mask:0xf\n\t"
        "s_nop 1\n\t"
        "v_add_f32_dpp %[p], %[p], %[p] row_ror:2 row_mask:0xf bank_mask:0xf\n\t"
        "s_nop 1\n\t"
        "v_add_f32_dpp %[p], %[p], %[p] row_ror:1 row_mask:0xf bank_mask:0xf\n\t"
        "s_nop 1\n\t"
        "v_fmac_f32 %[pk], %[p], %[m]"
        : [p]"+v"(p), [pk]"+v"(pk)
        : [r]"v"(r), [wo2]"v"(wo2), [m]"v"(m15));
}

__global__ __launch_bounds__(64, 1) void rnn_kernel(
    const float* __restrict__ x,
    const float* __restrict__ h0,
    const float* __restrict__ W_ih,
    const float* __restrict__ b_ih,
    const float* __restrict__ W_hh,
    const float* __restrict__ b_hh,
    const float* __restrict__ W_out,
    const float* __restrict__ b_out,
    float* __restrict__ out)
{
    const int tid = threadIdx.x;            // 0..63
    const int j   = tid & 15;               // lane-in-group; j<10 owns dim j
    const int b   = (blockIdx.x << 2) + (tid >> 4);
    const bool jv = (j < HID);
    const int jc  = jv ? j : 0;

    const float CC = 2.88539008177792681472f;   // 2*log2(e)

    // Raw per-lane weights (idle lanes zero).
    const float wih = jv ? W_ih[jc] : 0.0f;
    const float bj  = jv ? (b_ih[jc] + b_hh[jc]) : 0.0f;
    const float wo  = jv ? W_out[jc] : 0.0f;

    float wsh[16];
    float wsum = 0.0f;
#pragma unroll
    for (int N = 0; N < 16; ++N) {
        const int k = (j - N) & 15;
        wsh[N] = (jv && k < HID) ? W_hh[jc * HID + k] : 0.0f;
        wsum += wsh[N];
    }

    // r-form folded constants: a' = C*a with h = 1-2r absorbed.
    const float wih2 = CC * wih;                 // 0 for j>=10
    const float bj2  = CC * (bj + wsum);         // 0 for j>=10
    // Rotation weights. Lanes 0..9: -2C*W_hh (r-form). Lane 10: carries the
    // OUTPUT row, unscaled: w2[N] = -2*wo[(10-N)&15] so its accumulated
    // c0 = sum(-2*wo_k*r_k) = y - C0 (no exp scaling wanted). Lanes 11..15: 0.
    float w2[16];
#pragma unroll
    for (int N = 0; N < 16; ++N) {
        if (jv) {
            w2[N] = -2.0f * CC * wsh[N];
        } else if (j == 10) {
            const int k = (10 - N) & 15;
            w2[N] = (k < HID) ? (-2.0f * W_out[k]) : 0.0f;
        } else {
            w2[N] = 0.0f;
        }
    }
    const float wo2 = -2.0f * wo;                // finisher only
    float c0sum = b_out[0];
#pragma unroll
    for (int k = 0; k < HID; ++k) c0sum += W_out[k];   // C0 = sum(wo) + bo

    // Keep-masks.
    float km[16];
#pragma unroll
    for (int i = 0; i < 16; ++i) km[i] = (j == i) ? 1.0f : 0.0f;
    const float mzero = 0.0f;

    // r_0 = (1 - h_0)/2 ; idle lanes h0=0 -> r=0.5 (their fixed point).
    float rval = fmaf(-0.5f, jv ? h0[b * HID + jc] : 0.0f, 0.5f);
    float p = 0.0f, pk = 0.0f;

    const float* xb = x + b;
    float xA[UB], xB[UB];

    issue16(xA, xb);
    wait0_bind(xA);

    for (int t0 = 0; t0 < T_STEPS; t0 += 2 * UB) {
        // ---- half 1: consume xA, prefetch xB ----
        wait1_bind(xA);
        issue16(xB, xb + (size_t)(t0 + UB) * BATCH);
        run16<0>(rval, pk, xA, wih2, bj2, km, mzero, w2);
        finish_reduce(rval, p, pk, wo2, km[15]);
        out[(size_t)(t0 + j) * BATCH + b] = pk + c0sum;
        pk = 0.0f;

        // ---- half 2: consume xB, prefetch xA ----
        wait1_bind(xB);
        const float* xsrc = (t0 + 2 * UB < T_STEPS)
                          ? (xb + (size_t)(t0 + 2 * UB) * BATCH) : xb;
        issue16(xA, xsrc);
        run16<0>(rval, pk, xB, wih2, bj2, km, mzero, w2);
        finish_reduce(rval, p, pk, wo2, km[15]);
        out[(size_t)(t0 + UB + j) * BATCH + b] = pk + c0sum;
        pk = 0.0f;
    }

    // Drain the final speculative xA reload while registers are still bound
    // (async-clobber hazard, R6 post-mortem).
    wait0_bind(xA);

    // h_last: h = 1 - 2r
    if (jv) out[(size_t)T_STEPS * BATCH + (size_t)b * HID + j]
                = fmaf(-2.0f, rval, 1.0f);
}

extern "C" void kernel_launch(void* const* d_in, const int* in_sizes, int n_in,
                              void* d_out, int out_size, void* d_ws, size_t ws_size,
                              hipStream_t stream) {
    const float* x     = (const float*)d_in[0];
    const float* h0    = (const float*)d_in[1];
    const float* W_ih  = (const float*)d_in[2];
    const float* b_ih  = (const float*)d_in[3];
    const float* W_hh  = (const float*)d_in[4];
    const float* b_hh  = (const float*)d_in[5];
    const float* W_out = (const float*)d_in[6];
    const float* b_out = (const float*)d_in[7];

    rnn_kernel<<<BATCH / 4, 64, 0, stream>>>(
        x, h0, W_ih, b_ih, W_hh, b_hh, W_out, b_out, (float*)d_out);
}